// Round 15
// baseline (186.862 us; speedup 1.0000x reference)
//
#include <hip/hip_runtime.h>

typedef float f4 __attribute__((ext_vector_type(4)));

static constexpr int Hh = 256, Ww = 256, HW = Hh * Ww;
static constexpr int PLANES = 512;            // N*C
static constexpr int STRIPS = 4;
static constexpr int ROWS   = Hh / STRIPS;    // 64
static constexpr int DEPTH  = 10;
static constexpr int RB     = 4;              // rows advanced per sweep step
static constexpr int NSTEP  = (ROWS + 2 * DEPTH) / RB;   // 21

#if __has_builtin(__builtin_amdgcn_exp2f)
#define EXP2F(x) __builtin_amdgcn_exp2f(x)
#else
#define EXP2F(x) __expf((x) * 0.6931471805599453f)
#endif

static constexpr float LN2 = 0.6931471805599453f;
static constexpr float L2E = 1.4426950408889634f;
static constexpr float AZS = 10.0f * L2E;     // Z = AZS * z  (BETA+log2e folded)

// deg-2 minimax of ln(1+p), p = 2^(-|Z|); max(Z,0) folded into coefficients
static constexpr float A1c = 0.9897f;
static constexpr float A2c = -0.3059f;
static constexpr float TA = -0.12f * LN2;
static constexpr float TB = -0.08f * LN2;
static constexpr float TCA1 = -0.16f * A1c;
static constexpr float TCA2 = -0.16f * A2c;
static constexpr float UA = 0.06f * LN2;
static constexpr float UB = 0.04f * LN2;
static constexpr float UCA1 = 0.08f * A1c;
static constexpr float UCA2 = 0.08f * A2c;

// 5-6 insts: exp2(-|Z|) via src modifiers, then fma chain
__device__ __forceinline__ float tval_s(float Z) {
    float az = fabsf(Z);
    float p  = EXP2F(-az);
    float r  = fmaf(TCA2, p, TCA1);
    float s  = fmaf(r, p, 1.0f);
    return fmaf(TA, Z, fmaf(TB, az, s));
}
__device__ __forceinline__ float uval_s(float Z) {
    float az = fabsf(Z);
    float p  = EXP2F(-az);
    float r  = fmaf(UCA2, p, UCA1);
    float su = r * p;
    return fmaf(UA, Z, fmaf(UB, az, su));
}

// ---- per-chain step components; S is the chain suffix token (A or B) ----
#define CONSUME_PN(S)                                                        \
    _Pragma("unroll") for (int m = 0; m < RB; ++m)                           \
    { _Pragma("unroll") for (int i = 0; i < 4; ++i)                          \
        og##S[DEPTH + m][i] = AZS * pn##S[m][i]; }

#define LOADC(S, BORDER)                                                     \
    _Pragma("unroll") for (int t = DEPTH - 1; t >= 0; --t) {                 \
        int r = yS - DEPTH + t;                                              \
        if (BORDER) r = r < 0 ? 0 : (r > 255 ? 255 : r);                     \
        f4 v = *reinterpret_cast<const f4*>(op##S + r * Ww);                 \
        og##S[t][0]=v.x; og##S[t][1]=v.y; og##S[t][2]=v.z; og##S[t][3]=v.w;  \
    }

#define PREF(S)                                                              \
    _Pragma("unroll") for (int m = 0; m < RB; ++m) {                         \
        int r = yS + RB + m; r = r < 0 ? 0 : (r > 255 ? 255 : r);            \
        f4 v = *reinterpret_cast<const f4*>(op##S + r * Ww);                 \
        pn##S[m][0]=v.x; pn##S[m][1]=v.y; pn##S[m][2]=v.z; pn##S[m][3]=v.w;  \
    }

#define STAGE0(S, BORDER)                                                    \
    _Pragma("unroll") for (int m = 0; m < RB; ++m) {                         \
        const bool rv = !BORDER || (unsigned)(yS + m) < 256u;                \
        _Pragma("unroll") for (int i = 0; i < 4; ++i) {                      \
            float tv = tval_s(og##S[DEPTH + m][i]);                          \
            tin##S[m][i] = rv ? tv : 0.f;                                    \
        }                                                                    \
    }

#define SCALEOG(S)                                                           \
    _Pragma("unroll") for (int t = 0; t < DEPTH; ++t)                        \
    { _Pragma("unroll") for (int i = 0; i < 4; ++i) og##S[t][i] *= AZS; }

#define PERM(S)                                                              \
    _Pragma("unroll") for (int m = 0; m < RB; ++m) {                         \
        lf##S[m] = __int_as_float(__builtin_amdgcn_ds_bpermute(a_up, __float_as_int(tin##S[m][3]))); \
        rg##S[m] = __int_as_float(__builtin_amdgcn_ds_bpermute(a_dn, __float_as_int(tin##S[m][0]))); \
    }

#define HFMA(S)                                                              \
    _Pragma("unroll") for (int m = 0; m < RB; ++m) {                         \
        hn##S[m][0] = fmaf(w1s, tin##S[m][0], fmaf(w0s, tin##S[m][1], w0L * lf##S[m])); \
        hn##S[m][1] = fmaf(w1s, tin##S[m][1], w0s * (tin##S[m][0] + tin##S[m][2]));     \
        hn##S[m][2] = fmaf(w1s, tin##S[m][2], w0s * (tin##S[m][1] + tin##S[m][3]));     \
        hn##S[m][3] = fmaf(w1s, tin##S[m][3], fmaf(w0s, tin##S[m][2], w0R * rg##S[m])); \
    }

#define EVALS(S, BORDER)                                                     \
    _Pragma("unroll") for (int m = 0; m < RB; ++m) {                         \
        const bool rv = !BORDER || (unsigned)(yS - k + m) < 256u;            \
        _Pragma("unroll") for (int i = 0; i < 4; ++i) {                      \
            float h_im1 = (m == 0) ? hA##S[k-1][i] : (m == 1) ? hB##S[k-1][i] : hn##S[m-2][i]; \
            float h_i   = (m == 0) ? hB##S[k-1][i] : hn##S[m-1][i];          \
            float Z = fmaf(W0Z, h_im1 + hn##S[m][i],                         \
                      fmaf(W1Z, h_i, og##S[DEPTH - k + m][i]));              \
            if (k < DEPTH) { float tv = tval_s(Z); tin##S[m][i] = rv ? tv : 0.f; } \
            else           { tin##S[m][i] = uval_s(Z); }                     \
        }                                                                    \
    }                                                                        \
    _Pragma("unroll") for (int i = 0; i < 4; ++i) {                          \
        hA##S[k-1][i] = hn##S[2][i]; hB##S[k-1][i] = hn##S[3][i];            \
    }

#define STORE(S)                                                             \
    _Pragma("unroll") for (int m = 0; m < RB; ++m) {                         \
        const int r = yS - DEPTH + m;                                        \
        if (r >= y0 && r < y0 + ROWS) {                                      \
            f4 v; v.x=tin##S[m][0]; v.y=tin##S[m][1]; v.z=tin##S[m][2]; v.w=tin##S[m][3]; \
            *reinterpret_cast<f4*>(up##S + r * Ww) = v;                      \
        }                                                                    \
    }

// Two independent pipelines per wave, half-stage rotated: each chain's
// ds_bpermute wait (~120 cyc) is covered by the OTHER chain's eval block.
#define STEP2(BORDER) do {                                                   \
    float ogA[DEPTH+RB][4], ogB[DEPTH+RB][4];                                \
    float tinA[RB][4], tinB[RB][4];                                          \
    float hnA[RB][4],  hnB[RB][4];                                           \
    float lfA[RB], rgA[RB], lfB[RB], rgB[RB];                                \
    CONSUME_PN(A) CONSUME_PN(B)                                              \
    LOADC(A, BORDER) LOADC(B, BORDER)                                        \
    PREF(A) PREF(B)                                                          \
    asm volatile("" ::: "memory");                                           \
    STAGE0(A, BORDER) STAGE0(B, BORDER)                                      \
    SCALEOG(A) SCALEOG(B)                                                    \
    PERM(A) PERM(B)                                                          \
    _Pragma("unroll")                                                        \
    for (int k = 1; k <= DEPTH; ++k) {                                       \
        HFMA(A) EVALS(A, BORDER)                                             \
        if (k < DEPTH) { PERM(A) }                                           \
        HFMA(B) EVALS(B, BORDER)                                             \
        if (k < DEPTH) { PERM(B) }                                           \
    }                                                                        \
    STORE(A) STORE(B)                                                        \
} while (0)

// waves_per_eu(1,2): min=1 -> full 512-VGPR allocator budget for the ~2x
// pipeline state (R12 lesson: aggressive min collapses the allocator).
// Grid = 1024 waves = 1/SIMD; the ILP comes from the two in-wave chains,
// not from co-resident waves (R11-R14 showed those stall in lockstep).
__global__ __launch_bounds__(64)
__attribute__((amdgpu_waves_per_eu(1, 2)))
void k_fused(const float* __restrict__ o, const float* __restrict__ sigma,
             const float* __restrict__ lam, float* __restrict__ out) {
    const int lane   = threadIdx.x;
    const int bid    = blockIdx.x;            // 1024 blocks
    const int planeA = bid >> 2;              // 0..255
    const int planeB = planeA + 256;          // 256..511 (same channel)
    const int strip  = bid & 3;
    const int y0     = strip * ROWS;
    const int ch     = planeA & 63;           // == planeB & 63

    float s   = fmaxf(sigma[ch], 1e-6f);
    float eg  = __expf(-1.0f / (2.0f * s * s));
    float inv = 1.0f / (1.0f + 2.0f * eg);
    const float w0s = eg * inv, w1s = inv, l = lam[0];
    const float W0Z = -l * w0s * AZS;         // vertical taps, -lam and AZS folded
    const float W1Z = -l * w1s * AZS;
    const float w0L = (lane == 0)  ? 0.f : w0s;
    const float w0R = (lane == 63) ? 0.f : w0s;

    const float* opA = o   + planeA * HW + lane * 4;
    const float* opB = o   + planeB * HW + lane * 4;
    float*       upA = out + planeA * HW + lane * 4;
    float*       upB = out + planeB * HW + lane * 4;
    const int a_up = ((lane + 63) & 63) << 2;
    const int a_dn = ((lane + 1)  & 63) << 2;

    // per-stage h carries for both chains (rows r-1, r of conv'd t_{k-1})
    float hAA[DEPTH][4], hBA[DEPTH][4], hAB[DEPTH][4], hBB[DEPTH][4];
#pragma unroll
    for (int k = 0; k < DEPTH; ++k)
#pragma unroll
        for (int i = 0; i < 4; ++i) {
            hAA[k][i] = 0.f; hBA[k][i] = 0.f;
            hAB[k][i] = 0.f; hBB[k][i] = 0.f;
        }

    // prologue: prefetch first step's stage-0 rows for both chains
    float pnA[RB][4], pnB[RB][4];
#pragma unroll
    for (int m = 0; m < RB; ++m) {
        int r = y0 - DEPTH + m;
        r = r < 0 ? 0 : (r > 255 ? 255 : r);
        f4 va = *reinterpret_cast<const f4*>(opA + r * Ww);
        f4 vb = *reinterpret_cast<const f4*>(opB + r * Ww);
        pnA[m][0]=va.x; pnA[m][1]=va.y; pnA[m][2]=va.z; pnA[m][3]=va.w;
        pnB[m][0]=vb.x; pnB[m][1]=vb.y; pnB[m][2]=vb.z; pnB[m][3]=vb.w;
    }

    // border-step bounds (strip geometry identical for both chains)
    int jb0 = (20 - y0 + 3) / 4; if (jb0 < 0) jb0 = 0;
    int jb1 = (262 - y0) / 4 + 1; if (jb1 > NSTEP) jb1 = NSTEP;

    int j = 0;
#pragma unroll 1
    for (; j < jb0; ++j)  { const int yS = y0 - DEPTH + RB * j; STEP2(true);  }
#pragma unroll 1
    for (; j < jb1; ++j)  { const int yS = y0 - DEPTH + RB * j; STEP2(false); }
#pragma unroll 1
    for (; j < NSTEP; ++j){ const int yS = y0 - DEPTH + RB * j; STEP2(true);  }
}

extern "C" void kernel_launch(void* const* d_in, const int* in_sizes, int n_in,
                              void* d_out, int out_size, void* d_ws, size_t ws_size,
                              hipStream_t stream) {
    (void)in_sizes; (void)n_in; (void)out_size; (void)d_ws; (void)ws_size;
    const float* o     = (const float*)d_in[0];
    const float* sigma = (const float*)d_in[1];
    const float* lam   = (const float*)d_in[2];
    float* out = (float*)d_out;

    k_fused<<<PLANES * STRIPS / 2, 64, 0, stream>>>(o, sigma, lam, out);
}

// Round 16
// 150.307 us; speedup vs baseline: 1.2432x; 1.2432x over previous
//
#include <hip/hip_runtime.h>

typedef float f4 __attribute__((ext_vector_type(4)));

static constexpr int Hh = 256, Ww = 256, HW = Hh * Ww;
static constexpr int PLANES = 512;            // N*C
static constexpr int STRIPS = 4;
static constexpr int ROWS   = Hh / STRIPS;    // 64
static constexpr int DEPTH  = 10;
static constexpr int RB     = 4;              // rows advanced per sweep step
static constexpr int NSTEP  = (ROWS + 2 * DEPTH) / RB;   // 21

#if __has_builtin(__builtin_amdgcn_exp2f)
#define EXP2F(x) __builtin_amdgcn_exp2f(x)
#else
#define EXP2F(x) __expf((x) * 0.6931471805599453f)
#endif

static constexpr float LN2 = 0.6931471805599453f;
static constexpr float L2E = 1.4426950408889634f;
static constexpr float AZS = 10.0f * L2E;     // Z = AZS * z  (BETA+log2e folded)

// deg-2 minimax of ln(1+p), p = 2^(-|Z|); max(Z,0) folded into coefficients
// (error budget: absmax saturated at 2.0 across rounds; threshold 10.04)
static constexpr float A1c = 0.9897f;
static constexpr float A2c = -0.3059f;
static constexpr float TA = -0.12f * LN2;
static constexpr float TB = -0.08f * LN2;
static constexpr float TCA1 = -0.16f * A1c;
static constexpr float TCA2 = -0.16f * A2c;
static constexpr float UA = 0.06f * LN2;
static constexpr float UB = 0.04f * LN2;
static constexpr float UCA1 = 0.08f * A1c;
static constexpr float UCA2 = 0.08f * A2c;

// 6 ops: az, exp2, 4 fma
__device__ __forceinline__ float tval_s(float Z) {
    float az = fabsf(Z);
    float p  = EXP2F(-az);                    // neg folds into src modifier
    float r  = fmaf(TCA2, p, TCA1);
    float s  = fmaf(r, p, 1.0f);              // 1 + TC*ln(1+p)
    return fmaf(TA, Z, fmaf(TB, az, s));
}
// 6 ops
__device__ __forceinline__ float uval_s(float Z) {
    float az = fabsf(Z);
    float p  = EXP2F(-az);
    float r  = fmaf(UCA2, p, UCA1);
    float su = r * p;                         // UC*ln(1+p)
    return fmaf(UA, Z, fmaf(UB, az, su));
}

// One sweep step. BORDER is a literal; pnext[4][4] carries the next step's
// stage-0 rows (prefetched one full step ahead -> no vmcnt stall at stage 0).
#define STEP_BODY(BORDER) do {                                               \
    float og[DEPTH + RB][4];                                                 \
    /* stage-0 rows: consume prefetch (long since returned), scale to Z */   \
    _Pragma("unroll")                                                        \
    for (int m = 0; m < RB; ++m)                                             \
        { _Pragma("unroll") for (int i = 0; i < 4; ++i) og[DEPTH + m][i] = AZS * pnext[m][i]; } \
    /* issue current-step rows og[9]..og[0] in consumption order (raw) */    \
    _Pragma("unroll")                                                        \
    for (int t = DEPTH - 1; t >= 0; --t) {                                   \
        int r = yS - DEPTH + t;                                              \
        if (BORDER) r = r < 0 ? 0 : (r > 255 ? 255 : r);                     \
        f4 v = *reinterpret_cast<const f4*>(op_lane + r * Ww);               \
        og[t][0] = v.x; og[t][1] = v.y; og[t][2] = v.z; og[t][3] = v.w;      \
    }                                                                        \
    /* issue NEXT step's stage-0 prefetch (rows yS+4..yS+7, always clamped) */\
    _Pragma("unroll")                                                        \
    for (int m = 0; m < RB; ++m) {                                           \
        int r = yS + RB + m;                                                 \
        r = r < 0 ? 0 : (r > 255 ? 255 : r);                                 \
        f4 v = *reinterpret_cast<const f4*>(op_lane + r * Ww);               \
        pnext[m][0] = v.x; pnext[m][1] = v.y; pnext[m][2] = v.z; pnext[m][3] = v.w; \
    }                                                                        \
    asm volatile("" ::: "memory");               /* pin loads above compute */\
    float tin[RB][4];                                                        \
    _Pragma("unroll")                                                        \
    for (int m = 0; m < RB; ++m) {                                           \
        const bool rv = !BORDER || (unsigned)(yS + m) < 256u;                \
        _Pragma("unroll")                                                    \
        for (int i = 0; i < 4; ++i) {                                        \
            float tv = tval_s(og[DEPTH + m][i]);                             \
            tin[m][i] = rv ? tv : 0.f;                                       \
        }                                                                    \
    }                                                                        \
    /* scale current rows to Z-domain (loads now have ~stage-0 of cover) */  \
    _Pragma("unroll")                                                        \
    for (int t = 0; t < DEPTH; ++t)                                          \
        { _Pragma("unroll") for (int i = 0; i < 4; ++i) og[t][i] *= AZS; }   \
    _Pragma("unroll")                                                        \
    for (int k = 1; k <= DEPTH; ++k) {                                       \
        float hn[RB][4];                                                     \
        _Pragma("unroll")                                                    \
        for (int m = 0; m < RB; ++m) {                                       \
            float lft = __int_as_float(__builtin_amdgcn_ds_bpermute(a_up, __float_as_int(tin[m][3]))); \
            float rgt = __int_as_float(__builtin_amdgcn_ds_bpermute(a_dn, __float_as_int(tin[m][0]))); \
            hn[m][0] = fmaf(w1s, tin[m][0], fmaf(w0s, tin[m][1], w0L * lft)); \
            hn[m][1] = fmaf(w1s, tin[m][1], w0s * (tin[m][0] + tin[m][2]));  \
            hn[m][2] = fmaf(w1s, tin[m][2], w0s * (tin[m][1] + tin[m][3]));  \
            hn[m][3] = fmaf(w1s, tin[m][3], fmaf(w0s, tin[m][2], w0R * rgt)); \
        }                                                                    \
        _Pragma("unroll")                                                    \
        for (int m = 0; m < RB; ++m) {                                       \
            const bool rv = !BORDER || (unsigned)(yS - k + m) < 256u;        \
            _Pragma("unroll")                                                \
            for (int i = 0; i < 4; ++i) {                                    \
                float h_im1 = (m == 0) ? hA[k - 1][i] : (m == 1) ? hB[k - 1][i] : hn[m - 2][i]; \
                float h_i   = (m == 0) ? hB[k - 1][i] : hn[m - 1][i];        \
                float Z = fmaf(W0Z, h_im1 + hn[m][i],                        \
                          fmaf(W1Z, h_i, og[DEPTH - k + m][i]));             \
                if (k < DEPTH) { float tv = tval_s(Z); tin[m][i] = rv ? tv : 0.f; } \
                else           { tin[m][i] = uval_s(Z); }                    \
            }                                                                \
        }                                                                    \
        _Pragma("unroll")                                                    \
        for (int i = 0; i < 4; ++i) { hA[k - 1][i] = hn[2][i]; hB[k - 1][i] = hn[3][i]; } \
    }                                                                        \
    _Pragma("unroll")                                                        \
    for (int m = 0; m < RB; ++m) {                                           \
        const int r = yS - DEPTH + m;                                        \
        if (r >= y0 && r < y0 + ROWS) {                                      \
            f4 v; v.x = tin[m][0]; v.y = tin[m][1]; v.z = tin[m][2]; v.w = tin[m][3]; \
            *reinterpret_cast<f4*>(up_lane + r * Ww) = v;                    \
        }                                                                    \
    }                                                                        \
} while (0)

// R11 config exactly (152 us baseline: 2048 waves = 2/SIMD, VGPR=100, zero
// scratch) + ONE change: de-phase the two co-resident waves per SIMD.
// Both waves run identical code launched in lockstep -> they reach every
// stage's lgkmcnt(ds_bpermute) wait simultaneously and stall TOGETHER
// (~290 cyc/stage measured idle == bpermute round-trip). Dispatch fills all
// 1024 SIMDs once per 1024 single-wave WGs, so blocks >= grid/2 arrive as
// the second wave on their SIMD: sleep them ~320 cyc (half an eval block)
// so each wave's DS wait is covered by the other's eval block.
__global__ __launch_bounds__(64)
__attribute__((amdgpu_waves_per_eu(2, 2)))
void k_fused(const float* __restrict__ o, const float* __restrict__ sigma,
             const float* __restrict__ lam, float* __restrict__ out) {
    const int lane  = threadIdx.x;
    const int bid   = blockIdx.x;

    if (bid >= (PLANES * STRIPS) / 2) {
        __builtin_amdgcn_s_sleep(5);          // ~320 cycles, issued once
    }

    const int plane = bid >> 2;               // 512 planes
    const int strip = bid & 3;
    const int y0    = strip * ROWS;
    const int ch    = plane & 63;

    float s   = fmaxf(sigma[ch], 1e-6f);
    float eg  = __expf(-1.0f / (2.0f * s * s));
    float inv = 1.0f / (1.0f + 2.0f * eg);
    const float w0s = eg * inv, w1s = inv, l = lam[0];
    const float W0Z = -l * w0s * AZS;         // vertical taps, -lam and AZS folded
    const float W1Z = -l * w1s * AZS;
    // edge-lane masked taps: kill the per-stage cndmask on lft/rgt
    const float w0L = (lane == 0)  ? 0.f : w0s;
    const float w0R = (lane == 63) ? 0.f : w0s;

    const float* op_lane = o   + plane * HW + lane * 4;
    float*       up_lane = out + plane * HW + lane * 4;
    const int a_up = ((lane + 63) & 63) << 2;
    const int a_dn = ((lane + 1)  & 63) << 2;

    // per-stage h carries: rows (r-1, r) of conv'd t_{k-1}, in registers
    float hA[DEPTH][4], hB[DEPTH][4];
#pragma unroll
    for (int k = 0; k < DEPTH; ++k)
#pragma unroll
        for (int i = 0; i < 4; ++i) { hA[k][i] = 0.f; hB[k][i] = 0.f; }

    // prologue: prefetch first step's stage-0 rows (y0-10..y0-7, clamped;
    // OOB rows are zeroed by the border steps' rv select before use)
    float pnext[RB][4];
#pragma unroll
    for (int m = 0; m < RB; ++m) {
        int r = y0 - DEPTH + m;
        r = r < 0 ? 0 : (r > 255 ? 255 : r);
        f4 v = *reinterpret_cast<const f4*>(op_lane + r * Ww);
        pnext[m][0] = v.x; pnext[m][1] = v.y; pnext[m][2] = v.z; pnext[m][3] = v.w;
    }

    // border-step bounds: steps touching rows <0 (strip 0) or >255 (strip 3)
    int jb0 = (20 - y0 + 3) / 4; if (jb0 < 0) jb0 = 0;            // first interior
    int jb1 = (262 - y0) / 4 + 1; if (jb1 > NSTEP) jb1 = NSTEP;   // first trailing border

    int j = 0;
#pragma unroll 1
    for (; j < jb0; ++j)  { const int yS = y0 - DEPTH + RB * j; STEP_BODY(true);  }
#pragma unroll 1
    for (; j < jb1; ++j)  { const int yS = y0 - DEPTH + RB * j; STEP_BODY(false); }
#pragma unroll 1
    for (; j < NSTEP; ++j){ const int yS = y0 - DEPTH + RB * j; STEP_BODY(true);  }
}

extern "C" void kernel_launch(void* const* d_in, const int* in_sizes, int n_in,
                              void* d_out, int out_size, void* d_ws, size_t ws_size,
                              hipStream_t stream) {
    (void)in_sizes; (void)n_in; (void)out_size; (void)d_ws; (void)ws_size;
    const float* o     = (const float*)d_in[0];
    const float* sigma = (const float*)d_in[1];
    const float* lam   = (const float*)d_in[2];
    float* out = (float*)d_out;

    k_fused<<<PLANES * STRIPS, 64, 0, stream>>>(o, sigma, lam, out);
}